// Round 1
// baseline (619.797 us; speedup 1.0000x reference)
//
#include <hip/hip_runtime.h>
#include <hip/hip_bf16.h>

#define DD 63
#define NSU 8

// Static device scratch (no hipMalloc allowed). Rewritten every call -> deterministic.
__device__ float g_F[DD * DD * DD];     // structure constants f[a][b][c]
__device__ float g_Kt[64 * 64];         // Kt[i][j] = 0.01*(M+H)[i][j] + 1.01*delta(i,j)

// ---------------------------------------------------------------------------
// Kernel 1: structure constants f_abc = Im(Tr([La,Lb]Lc))/4
// grid = 63*63 blocks (one per (a,b)), 64 threads
// ---------------------------------------------------------------------------
__device__ __forceinline__ void fill_L(int a, float (*re)[NSU], float (*im)[NSU]) {
    if (a < 56) {
        int p = a >> 1;
        int j = 0, rem = p;
        while (rem >= 7 - j) { rem -= 7 - j; ++j; }
        int k = j + 1 + rem;
        if ((a & 1) == 0) { re[j][k] = 1.f; re[k][j] = 1.f; }
        else             { im[j][k] = -1.f; im[k][j] = 1.f; }
    } else {
        int l = a - 55;
        float c = sqrtf(2.f / (float)(l * (l + 1)));
        for (int j = 0; j < l; ++j) re[j][j] = c;
        re[l][l] = -(float)l * c;
    }
}

__global__ __launch_bounds__(64) void struct_f_kernel() {
    __shared__ float Ar[NSU][NSU], Ai[NSU][NSU], Br[NSU][NSU], Bi[NSU][NSU];
    __shared__ float Cr[NSU][NSU], Ci[NSU][NSU];
    const int t = threadIdx.x;
    const int a = blockIdx.x / DD, b = blockIdx.x % DD;
    const int r = t >> 3, c = t & 7;
    Ar[r][c] = 0.f; Ai[r][c] = 0.f; Br[r][c] = 0.f; Bi[r][c] = 0.f;
    __syncthreads();
    if (t == 0) fill_L(a, Ar, Ai);
    if (t == 1) fill_L(b, Br, Bi);
    __syncthreads();
    // comm = La*Lb - Lb*La (complex), entry (r,c)
    float pr = 0.f, pi = 0.f, qr = 0.f, qi = 0.f;
    #pragma unroll
    for (int k = 0; k < NSU; ++k) {
        pr += Ar[r][k] * Br[k][c] - Ai[r][k] * Bi[k][c];
        pi += Ar[r][k] * Bi[k][c] + Ai[r][k] * Br[k][c];
        qr += Br[r][k] * Ar[k][c] - Bi[r][k] * Ai[k][c];
        qi += Br[r][k] * Ai[k][c] + Bi[r][k] * Ar[k][c];
    }
    Cr[r][c] = pr - qr;
    Ci[r][c] = pi - qi;
    __syncthreads();
    if (t < DD) {
        float im;
        if (t < 56) {
            int p = t >> 1;
            int j = 0, rem = p;
            while (rem >= 7 - j) { rem -= 7 - j; ++j; }
            int k = j + 1 + rem;
            if ((t & 1) == 0) im = Ci[j][k] + Ci[k][j];          // sym: Im(comm[j][k]+comm[k][j])
            else              im = Cr[j][k] - Cr[k][j];          // antisym: Im(i*(comm[jk]-comm[kj]))
        } else {
            int l = t - 55;
            float cd = sqrtf(2.f / (float)(l * (l + 1)));
            float s = 0.f;
            for (int j = 0; j < l; ++j) s += Ci[j][j];
            im = cd * s - (float)l * cd * Ci[l][l];
        }
        g_F[(a * DD + b) * DD + t] = 0.25f * im;
    }
}

// ---------------------------------------------------------------------------
// Kernel 2: build Kt.  grid = 63 blocks (one per output row m), 256 threads.
// Kt[m][n] = 0.01*( -4*(N/tr)*sum_{ik}A1[i,k]*f[n,i,k] + 8*sum_k f[k,m,n]*w[k] )
//            + 1.01*delta(m,n),   A1[i,k] = sum_j cc[i,j]*f[m,j,k], cc = v^T v
// ---------------------------------------------------------------------------
__global__ __launch_bounds__(256) void build_kt_kernel(const float* __restrict__ r_x,
                                                       const float* __restrict__ r_y,
                                                       const float* __restrict__ Np,
                                                       const float* __restrict__ omega) {
    __shared__ float v[DD * DD];
    __shared__ float cc[DD * DD];
    __shared__ float A1[DD * DD];
    __shared__ float s_scale;
    const int t = threadIdx.x;
    const int m = blockIdx.x;

    for (int idx = t; idx < DD * DD; idx += 256) {
        int i = idx / DD, j = idx % DD;
        float val = 0.f;
        if (j > i)      val = r_y[62 * i - (i * (i - 1)) / 2 + (j - i - 1)];
        else if (j == i) val = r_x[63 * i - (i * (i - 1)) / 2];
        v[idx] = val;
    }
    __syncthreads();
    for (int idx = t; idx < DD * DD; idx += 256) {
        int i = idx / DD, j = idx % DD;
        float s = 0.f;
        for (int k = 0; k < DD; ++k) s = fmaf(v[k * DD + i], v[k * DD + j], s);
        cc[idx] = s;
    }
    __syncthreads();
    if (t == 0) {
        float tr = 0.f;
        for (int i = 0; i < DD; ++i) tr += cc[i * DD + i];
        s_scale = Np[0] / tr;
    }
    __syncthreads();
    const float* __restrict__ Fm = g_F + m * (DD * DD);
    for (int idx = t; idx < DD * DD; idx += 256) {
        int i = idx / DD, k = idx % DD;
        float s = 0.f;
        for (int j = 0; j < DD; ++j) s = fmaf(cc[i * DD + j], Fm[j * DD + k], s);
        A1[idx] = s;
    }
    __syncthreads();
    if (t < DD) {
        const int n = t;
        const float* __restrict__ Fn = g_F + n * (DD * DD);
        float s = 0.f;
        for (int idx = 0; idx < DD * DD; ++idx) s = fmaf(A1[idx], Fn[idx], s);
        float H = 0.f;
        for (int k = 0; k < DD; ++k) H = fmaf(g_F[k * (DD * DD) + m * DD + n], omega[k], H);
        float val = 0.01f * (-4.f * s_scale * s + 8.f * H) + ((m == n) ? 1.01f : 0.f);
        g_Kt[m * 64 + n] = val;
    }
}

// ---------------------------------------------------------------------------
// Kernel 3: out[b,i] = sum_j x[b,j] * Kt[i][j]  (Kt already includes 1.01*I)
// 256 rows per block; thread t owns row t. x row in VGPRs, Kt via scalar loads.
// ---------------------------------------------------------------------------
__global__ __launch_bounds__(256) void apply_kernel(const float* __restrict__ x,
                                                    float* __restrict__ out) {
    __shared__ __align__(16) float tile[256 * DD];   // 63 KB
    const int t = threadIdx.x;
    const size_t base = (size_t)blockIdx.x * (256 * DD);

    // stage in: 16128 contiguous floats, coalesced float4
    const float4* __restrict__ gsrc = (const float4*)(x + base);
    float4* __restrict__ ltile = (float4*)tile;
    #pragma unroll
    for (int it = 0; it < 16; ++it) {
        int idx = t + it * 256;
        if (idx < 4032) ltile[idx] = gsrc[idx];
    }
    __syncthreads();

    // row -> registers
    float xr[DD];
    #pragma unroll
    for (int j = 0; j < DD; ++j) xr[j] = tile[t * DD + j];
    __syncthreads();

    // 8 chunks of 8 output columns (starts 0,8,...,48,55 -> col 55 computed twice)
    for (int cs = 0; cs < 8; ++cs) {
        const int s0 = (cs == 7) ? 55 : cs * 8;
        float a0 = 0.f, a1 = 0.f, a2 = 0.f, a3 = 0.f, a4 = 0.f, a5 = 0.f, a6 = 0.f, a7 = 0.f;
        const float* __restrict__ K0 = g_Kt + (s0 + 0) * 64;
        const float* __restrict__ K1 = g_Kt + (s0 + 1) * 64;
        const float* __restrict__ K2 = g_Kt + (s0 + 2) * 64;
        const float* __restrict__ K3 = g_Kt + (s0 + 3) * 64;
        const float* __restrict__ K4 = g_Kt + (s0 + 4) * 64;
        const float* __restrict__ K5 = g_Kt + (s0 + 5) * 64;
        const float* __restrict__ K6 = g_Kt + (s0 + 6) * 64;
        const float* __restrict__ K7 = g_Kt + (s0 + 7) * 64;
        #pragma unroll
        for (int j = 0; j < DD; ++j) {
            const float xv = xr[j];
            a0 = fmaf(xv, K0[j], a0);
            a1 = fmaf(xv, K1[j], a1);
            a2 = fmaf(xv, K2[j], a2);
            a3 = fmaf(xv, K3[j], a3);
            a4 = fmaf(xv, K4[j], a4);
            a5 = fmaf(xv, K5[j], a5);
            a6 = fmaf(xv, K6[j], a6);
            a7 = fmaf(xv, K7[j], a7);
        }
        float* __restrict__ dst = tile + t * DD + s0;
        dst[0] = a0; dst[1] = a1; dst[2] = a2; dst[3] = a3;
        dst[4] = a4; dst[5] = a5; dst[6] = a6; dst[7] = a7;
    }
    __syncthreads();

    // flush: coalesced float4
    float4* __restrict__ gdst = (float4*)(out + base);
    #pragma unroll
    for (int it = 0; it < 16; ++it) {
        int idx = t + it * 256;
        if (idx < 4032) gdst[idx] = ltile[idx];
    }
}

// ---------------------------------------------------------------------------
extern "C" void kernel_launch(void* const* d_in, const int* in_sizes, int n_in,
                              void* d_out, int out_size, void* d_ws, size_t ws_size,
                              hipStream_t stream) {
    const float* x     = (const float*)d_in[0];
    const float* r_x   = (const float*)d_in[1];
    const float* r_y   = (const float*)d_in[2];
    const float* Np    = (const float*)d_in[3];
    const float* omega = (const float*)d_in[4];
    float* out = (float*)d_out;

    const int rows = in_sizes[0] / DD;          // 1048576
    const int nblocks = rows / 256;             // 4096

    struct_f_kernel<<<DD * DD, 64, 0, stream>>>();
    build_kt_kernel<<<DD, 256, 0, stream>>>(r_x, r_y, Np, omega);
    apply_kernel<<<nblocks, 256, 0, stream>>>(x, out);
}

// Round 2
// 554.706 us; speedup vs baseline: 1.1173x; 1.1173x over previous
//
#include <hip/hip_runtime.h>

#define DD 63
#define DD2 (DD * DD)   // 3969
#define NSU 8

typedef __attribute__((ext_vector_type(16))) float floatx16;

// Device-global scratch (rewritten every call -> deterministic).
__device__ float g_F[DD2 * DD];      // f[a][b][c] = g_F[(a*63+b)*63+c]
__device__ float g_cc[DD2];          // cc = v^T v
__device__ float g_scale;            // N / tr(cc)
__device__ float g_Kt[64 * 64];      // Kt[i][j] (row stride 64): 0.01*(M+H) + 1.01*I

// ---------------------------------------------------------------------------
// fill one Gell-Mann matrix (re/im parts) into 8x8 shared arrays
// ---------------------------------------------------------------------------
__device__ __forceinline__ void fill_L(int a, float (*re)[NSU], float (*im)[NSU]) {
    if (a < 56) {
        int p = a >> 1;
        int j = 0, rem = p;
        while (rem >= 7 - j) { rem -= 7 - j; ++j; }
        int k = j + 1 + rem;
        if ((a & 1) == 0) { re[j][k] = 1.f; re[k][j] = 1.f; }
        else             { im[j][k] = -1.f; im[k][j] = 1.f; }
    } else {
        int l = a - 55;
        float c = sqrtf(2.f / (float)(l * (l + 1)));
        for (int j = 0; j < l; ++j) re[j][j] = c;
        re[l][l] = -(float)l * c;
    }
}

// ---------------------------------------------------------------------------
// Kernel 1 (merged): blocks 0..3968 compute structure constants f_ab* ;
// block 3969 computes cc = v^T v and the trace scale.
// ---------------------------------------------------------------------------
__global__ __launch_bounds__(256) void setup1_kernel(const float* __restrict__ r_x,
                                                     const float* __restrict__ r_y,
                                                     const float* __restrict__ Np) {
    const int t = threadIdx.x;
    if (blockIdx.x < DD2) {
        // ---- structure constants for (a,b) ----
        __shared__ float Ar[NSU][NSU], Ai[NSU][NSU], Br[NSU][NSU], Bi[NSU][NSU];
        __shared__ float Cr[NSU][NSU], Ci[NSU][NSU];
        const int a = blockIdx.x / DD, b = blockIdx.x % DD;
        const int r = t >> 3, c = t & 7;
        if (t < 64) { Ar[r][c] = 0.f; Ai[r][c] = 0.f; Br[r][c] = 0.f; Bi[r][c] = 0.f; }
        __syncthreads();
        if (t == 0) fill_L(a, Ar, Ai);
        if (t == 1) fill_L(b, Br, Bi);
        __syncthreads();
        if (t < 64) {
            float pr = 0.f, pi = 0.f, qr = 0.f, qi = 0.f;
            #pragma unroll
            for (int k = 0; k < NSU; ++k) {
                pr += Ar[r][k] * Br[k][c] - Ai[r][k] * Bi[k][c];
                pi += Ar[r][k] * Bi[k][c] + Ai[r][k] * Br[k][c];
                qr += Br[r][k] * Ar[k][c] - Bi[r][k] * Ai[k][c];
                qi += Br[r][k] * Ai[k][c] + Bi[r][k] * Ar[k][c];
            }
            Cr[r][c] = pr - qr;
            Ci[r][c] = pi - qi;
        }
        __syncthreads();
        if (t < DD) {
            float im;
            if (t < 56) {
                int p = t >> 1;
                int j = 0, rem = p;
                while (rem >= 7 - j) { rem -= 7 - j; ++j; }
                int k = j + 1 + rem;
                if ((t & 1) == 0) im = Ci[j][k] + Ci[k][j];
                else              im = Cr[j][k] - Cr[k][j];
            } else {
                int l = t - 55;
                float cd = sqrtf(2.f / (float)(l * (l + 1)));
                float s = 0.f;
                for (int j = 0; j < l; ++j) s += Ci[j][j];
                im = cd * s - (float)l * cd * Ci[l][l];
            }
            g_F[(a * DD + b) * DD + t] = 0.25f * im;
        }
    } else {
        // ---- cc = v^T v, scale = N / tr(cc) ----
        __shared__ float v[DD2];
        __shared__ float ccs[DD2];
        for (int idx = t; idx < DD2; idx += 256) {
            int i = idx / DD, j = idx % DD;
            float val = 0.f;
            if (j > i)       val = r_y[62 * i - (i * (i - 1)) / 2 + (j - i - 1)];
            else if (j == i) val = r_x[63 * i - (i * (i - 1)) / 2];
            v[idx] = val;
        }
        __syncthreads();
        for (int idx = t; idx < DD2; idx += 256) {
            int i = idx / DD, j = idx % DD;
            float s = 0.f;
            for (int k = 0; k < DD; ++k) s = fmaf(v[k * DD + i], v[k * DD + j], s);
            ccs[idx] = s;
            g_cc[idx] = s;
        }
        __syncthreads();
        if (t == 0) {
            float tr = 0.f;
            for (int i = 0; i < DD; ++i) tr += ccs[i * DD + i];
            g_scale = Np[0] / tr;
        }
    }
}

// ---------------------------------------------------------------------------
// Kernel 2: 63 blocks, block m computes row m of Kt (parallel reductions).
// ---------------------------------------------------------------------------
__global__ __launch_bounds__(256) void build_kt_kernel(const float* __restrict__ omega) {
    __shared__ float cc[DD2];
    __shared__ float A1[DD2];
    __shared__ float red[256];
    const int t = threadIdx.x;
    const int m = blockIdx.x;

    for (int idx = t; idx < DD2; idx += 256) cc[idx] = g_cc[idx];
    __syncthreads();

    const float* __restrict__ Fm = g_F + m * DD2;
    for (int idx = t; idx < DD2; idx += 256) {
        int i = idx / DD, k = idx % DD;
        float s = 0.f;
        for (int j = 0; j < DD; ++j) s = fmaf(cc[i * DD + j], Fm[j * DD + k], s);
        A1[idx] = s;
    }
    __syncthreads();

    // M_row[n] = sum_idx A1[idx] * F[n][idx]; 4 partial threads per n
    float part = 0.f;
    if (t < 252) {
        const int n = t >> 2, p = t & 3;
        const float* __restrict__ Fn = g_F + n * DD2;
        for (int idx = p; idx < DD2; idx += 4) part = fmaf(A1[idx], Fn[idx], part);
    }
    red[t] = part;
    __syncthreads();

    if (t < DD) {
        const int n = t;
        float s = red[4 * n] + red[4 * n + 1] + red[4 * n + 2] + red[4 * n + 3];
        float H = 0.f;
        for (int k = 0; k < DD; ++k) H = fmaf(g_F[k * DD2 + m * DD + n], omega[k], H);
        g_Kt[m * 64 + n] = 0.01f * (-4.f * g_scale * s + 8.f * H) + ((m == n) ? 1.01f : 0.f);
    }
    if (t == 63) g_Kt[m * 64 + 63] = 0.f;   // pad column (loaded by s_load, never used)
}

// ---------------------------------------------------------------------------
// Kernel 3: out[b,i] = sum_j Kt[i][j] * x[b,j].
// One row per thread (63 VGPRs); Kt row in SGPRs via s_load_dwordx16;
// inner loop is pure v_fmac_f32 v,s,v with two independent chains.
// ---------------------------------------------------------------------------
__global__ __launch_bounds__(256) void apply_kernel(const float* __restrict__ x,
                                                    float* __restrict__ out) {
    __shared__ __align__(16) float tile[256 * DD];   // 63 KB -> 2 blocks/CU
    const int t = threadIdx.x;
    const size_t base = (size_t)blockIdx.x * (256 * DD);

    // stage in: 16128 contiguous floats, coalesced float4
    const float4* __restrict__ gsrc = (const float4*)(x + base);
    float4* __restrict__ ltile = (float4*)tile;
    #pragma unroll
    for (int it = 0; it < 16; ++it) {
        int idx = t + it * 256;
        if (idx < 4032) ltile[idx] = gsrc[idx];
    }
    __syncthreads();

    // row -> registers
    float xr[DD];
    #pragma unroll
    for (int j = 0; j < DD; ++j) xr[j] = tile[t * DD + j];
    __syncthreads();

    const float* kt = g_Kt;
    #pragma unroll 1
    for (int i = 0; i < DD; ++i) {
        const float* kp = kt + (i << 6);
        floatx16 k0, k1, k2, k3;
        asm volatile(
            "s_load_dwordx16 %0, %4, 0x0\n\t"
            "s_load_dwordx16 %1, %4, 0x40\n\t"
            "s_load_dwordx16 %2, %4, 0x80\n\t"
            "s_load_dwordx16 %3, %4, 0xc0"
            : "=s"(k0), "=s"(k1), "=s"(k2), "=s"(k3)
            : "s"(kp));
        asm volatile("s_waitcnt lgkmcnt(0)"
            : "+s"(k0), "+s"(k1), "+s"(k2), "+s"(k3));

        #define KV(j) ((j) < 16 ? k0[(j)] : (j) < 32 ? k1[(j) - 16] : (j) < 48 ? k2[(j) - 32] : k3[(j) - 48])
        float accA = 0.f, accB = 0.f;
        #pragma unroll
        for (int j = 0; j < 31; ++j)  accA = fmaf(xr[j], KV(j), accA);
        #pragma unroll
        for (int j = 31; j < 63; ++j) accB = fmaf(xr[j], KV(j), accB);
        #undef KV
        tile[t * DD + i] = accA + accB;
    }
    __syncthreads();

    // flush: coalesced float4
    float4* __restrict__ gdst = (float4*)(out + base);
    #pragma unroll
    for (int it = 0; it < 16; ++it) {
        int idx = t + it * 256;
        if (idx < 4032) gdst[idx] = ltile[idx];
    }
}

// ---------------------------------------------------------------------------
extern "C" void kernel_launch(void* const* d_in, const int* in_sizes, int n_in,
                              void* d_out, int out_size, void* d_ws, size_t ws_size,
                              hipStream_t stream) {
    const float* x     = (const float*)d_in[0];
    const float* r_x   = (const float*)d_in[1];
    const float* r_y   = (const float*)d_in[2];
    const float* Np    = (const float*)d_in[3];
    const float* omega = (const float*)d_in[4];
    float* out = (float*)d_out;

    const int rows = in_sizes[0] / DD;          // 1048576
    const int nblocks = rows / 256;             // 4096

    setup1_kernel<<<DD2 + 1, 256, 0, stream>>>(r_x, r_y, Np);
    build_kt_kernel<<<DD, 256, 0, stream>>>(omega);
    apply_kernel<<<nblocks, 256, 0, stream>>>(x, out);
}

// Round 3
// 552.341 us; speedup vs baseline: 1.1221x; 1.0043x over previous
//
#include <hip/hip_runtime.h>

#define DD 63
#define DD2 (DD * DD)   // 3969
#define NSU 8

// Device-global scratch (rewritten every call -> deterministic).
__device__ float g_F[DD2 * DD];      // f[a][b][c] = g_F[(a*63+b)*63+c]
__device__ float g_Kt[64 * 64];      // Kt[i][j] (row stride 64): 0.01*(M+H) + 1.01*I

// ---------------------------------------------------------------------------
// fill one Gell-Mann matrix (re/im parts) into 8x8 shared arrays
// ---------------------------------------------------------------------------
__device__ __forceinline__ void fill_L(int a, float (*re)[NSU], float (*im)[NSU]) {
    if (a < 56) {
        int p = a >> 1;
        int j = 0, rem = p;
        while (rem >= 7 - j) { rem -= 7 - j; ++j; }
        int k = j + 1 + rem;
        if ((a & 1) == 0) { re[j][k] = 1.f; re[k][j] = 1.f; }
        else             { im[j][k] = -1.f; im[k][j] = 1.f; }
    } else {
        int l = a - 55;
        float c = sqrtf(2.f / (float)(l * (l + 1)));
        for (int j = 0; j < l; ++j) re[j][j] = c;
        re[l][l] = -(float)l * c;
    }
}

// ---------------------------------------------------------------------------
// Kernel 1: structure constants. 3969 blocks x 64 threads (lean).
// ---------------------------------------------------------------------------
__global__ __launch_bounds__(64) void struct_f_kernel() {
    __shared__ float Ar[NSU][NSU], Ai[NSU][NSU], Br[NSU][NSU], Bi[NSU][NSU];
    __shared__ float Cr[NSU][NSU], Ci[NSU][NSU];
    const int t = threadIdx.x;
    const int a = blockIdx.x / DD, b = blockIdx.x % DD;
    const int r = t >> 3, c = t & 7;
    Ar[r][c] = 0.f; Ai[r][c] = 0.f; Br[r][c] = 0.f; Bi[r][c] = 0.f;
    __syncthreads();
    if (t == 0) fill_L(a, Ar, Ai);
    if (t == 1) fill_L(b, Br, Bi);
    __syncthreads();
    float pr = 0.f, pi = 0.f, qr = 0.f, qi = 0.f;
    #pragma unroll
    for (int k = 0; k < NSU; ++k) {
        pr += Ar[r][k] * Br[k][c] - Ai[r][k] * Bi[k][c];
        pi += Ar[r][k] * Bi[k][c] + Ai[r][k] * Br[k][c];
        qr += Br[r][k] * Ar[k][c] - Bi[r][k] * Ai[k][c];
        qi += Br[r][k] * Ai[k][c] + Bi[r][k] * Ar[k][c];
    }
    Cr[r][c] = pr - qr;
    Ci[r][c] = pi - qi;
    __syncthreads();
    if (t < DD) {
        float im;
        if (t < 56) {
            int p = t >> 1;
            int j = 0, rem = p;
            while (rem >= 7 - j) { rem -= 7 - j; ++j; }
            int k = j + 1 + rem;
            if ((t & 1) == 0) im = Ci[j][k] + Ci[k][j];
            else              im = Cr[j][k] - Cr[k][j];
        } else {
            int l = t - 55;
            float cd = sqrtf(2.f / (float)(l * (l + 1)));
            float s = 0.f;
            for (int j = 0; j < l; ++j) s += Ci[j][j];
            im = cd * s - (float)l * cd * Ci[l][l];
        }
        g_F[(a * DD + b) * DD + t] = 0.25f * im;
    }
}

// ---------------------------------------------------------------------------
// Kernel 2: self-contained Kt build. 63 blocks (block = output row m) x 256.
// Each block: v, cc, scale (redundant, ~us), stage F[m] to LDS, A1, then
// M1 row via coalesced global F[n] reads + wave shuffle reduction, H, Kt.
// ---------------------------------------------------------------------------
__global__ __launch_bounds__(256) void build_kt_kernel(const float* __restrict__ r_x,
                                                       const float* __restrict__ r_y,
                                                       const float* __restrict__ Np,
                                                       const float* __restrict__ omega) {
    __shared__ float v[DD2];
    __shared__ float cc[DD2];
    __shared__ float Fm[DD2];
    __shared__ float A1[DD2];
    __shared__ float Mrow[64];
    __shared__ float s_scale;
    const int t = threadIdx.x;
    const int m = blockIdx.x;

    for (int idx = t; idx < DD2; idx += 256) {
        int i = idx / DD, j = idx % DD;
        float val = 0.f;
        if (j > i)       val = r_y[62 * i - (i * (i - 1)) / 2 + (j - i - 1)];
        else if (j == i) val = r_x[63 * i - (i * (i - 1)) / 2];
        v[idx] = val;
    }
    // stage F[m] while v is being built (independent)
    for (int idx = t; idx < DD2; idx += 256) Fm[idx] = g_F[m * DD2 + idx];
    __syncthreads();

    for (int idx = t; idx < DD2; idx += 256) {
        int i = idx / DD, j = idx % DD;
        float s = 0.f;
        for (int k = 0; k < DD; ++k) s = fmaf(v[k * DD + i], v[k * DD + j], s);
        cc[idx] = s;
    }
    __syncthreads();
    if (t == 0) {
        float tr = 0.f;
        for (int i = 0; i < DD; ++i) tr += cc[i * DD + i];
        s_scale = Np[0] / tr;
    }
    __syncthreads();

    // A1[i,k] = sum_j cc[i,j] * Fm[j,k]
    for (int idx = t; idx < DD2; idx += 256) {
        int i = idx / DD, k = idx % DD;
        float s = 0.f;
        for (int j = 0; j < DD; ++j) s = fmaf(cc[i * DD + j], Fm[j * DD + k], s);
        A1[idx] = s;
    }
    __syncthreads();

    // Mrow[n] = sum_idx A1[idx] * F[n][idx]; wave w owns n = w*16..w*16+15.
    const int w = t >> 6, lane = t & 63;
    for (int q = 0; q < 16; ++q) {
        const int n = w * 16 + q;
        if (n < DD) {
            const float* __restrict__ Fn = g_F + n * DD2;
            float p = 0.f;
            for (int idx = lane; idx < DD2; idx += 64) p = fmaf(A1[idx], Fn[idx], p);
            #pragma unroll
            for (int off = 32; off > 0; off >>= 1) p += __shfl_down(p, off);
            if (lane == 0) Mrow[n] = p;
        }
    }
    __syncthreads();

    if (t < DD) {
        const int n = t;
        float H = 0.f;
        for (int k = 0; k < DD; ++k) H = fmaf(g_F[k * DD2 + m * DD + n], omega[k], H);
        g_Kt[m * 64 + n] = 0.01f * (-4.f * s_scale * Mrow[n] + 8.f * H) + ((m == n) ? 1.01f : 0.f);
    }
    if (t == 63) g_Kt[m * 64 + 63] = 0.f;   // pad column
}

// ---------------------------------------------------------------------------
// Kernel 3: out[b,i] = sum_j Kt[i][j] * x[b,j].
// Kt staged in LDS (uniform broadcast ds_read_b128, in-order, pipelinable).
// One batch row per thread in VGPRs; 4 accumulator chains.
// ---------------------------------------------------------------------------
__global__ __launch_bounds__(256) void apply_kernel(const float* __restrict__ x,
                                                    float* __restrict__ out) {
    __shared__ __align__(16) float tile[256 * DD];   // 63 KB
    __shared__ __align__(16) float sKt[64 * 64];     // 16 KB  (total 80.9 KB -> 2 blocks/CU)
    const int t = threadIdx.x;
    const size_t base = (size_t)blockIdx.x * (256 * DD);

    // stage x tile: 16128 contiguous floats, coalesced float4
    const float4* __restrict__ gsrc = (const float4*)(x + base);
    float4* __restrict__ ltile = (float4*)tile;
    #pragma unroll
    for (int it = 0; it < 16; ++it) {
        int idx = t + it * 256;
        if (idx < 4032) ltile[idx] = gsrc[idx];
    }
    // stage Kt: 4096 floats
    const float4* __restrict__ gk = (const float4*)g_Kt;
    float4* __restrict__ lk = (float4*)sKt;
    #pragma unroll
    for (int it = 0; it < 4; ++it) lk[t + it * 256] = gk[t + it * 256];
    __syncthreads();

    // own row -> registers (stride 63 dwords across lanes: conflict-free)
    float xr[DD];
    #pragma unroll
    for (int j = 0; j < DD; ++j) xr[j] = tile[t * DD + j];

    // no sync needed: each thread reads/writes only its own tile row
    #pragma unroll 2
    for (int i = 0; i < DD; ++i) {
        const float4* __restrict__ kr = (const float4*)(sKt + (i << 6));
        float a0 = 0.f, a1 = 0.f, a2 = 0.f, a3 = 0.f;
        #pragma unroll
        for (int j4 = 0; j4 < 15; ++j4) {
            float4 kv = kr[j4];
            a0 = fmaf(xr[4 * j4 + 0], kv.x, a0);
            a1 = fmaf(xr[4 * j4 + 1], kv.y, a1);
            a2 = fmaf(xr[4 * j4 + 2], kv.z, a2);
            a3 = fmaf(xr[4 * j4 + 3], kv.w, a3);
        }
        float4 kv = kr[15];                 // j = 60,61,62 (w unused)
        a0 = fmaf(xr[60], kv.x, a0);
        a1 = fmaf(xr[61], kv.y, a1);
        a2 = fmaf(xr[62], kv.z, a2);
        tile[t * DD + i] = (a0 + a1) + (a2 + a3);
    }
    __syncthreads();

    // flush: coalesced float4
    float4* __restrict__ gdst = (float4*)(out + base);
    #pragma unroll
    for (int it = 0; it < 16; ++it) {
        int idx = t + it * 256;
        if (idx < 4032) gdst[idx] = ltile[idx];
    }
}

// ---------------------------------------------------------------------------
extern "C" void kernel_launch(void* const* d_in, const int* in_sizes, int n_in,
                              void* d_out, int out_size, void* d_ws, size_t ws_size,
                              hipStream_t stream) {
    const float* x     = (const float*)d_in[0];
    const float* r_x   = (const float*)d_in[1];
    const float* r_y   = (const float*)d_in[2];
    const float* Np    = (const float*)d_in[3];
    const float* omega = (const float*)d_in[4];
    float* out = (float*)d_out;

    const int rows = in_sizes[0] / DD;          // 1048576
    const int nblocks = rows / 256;             // 4096

    struct_f_kernel<<<DD2, 64, 0, stream>>>();
    build_kt_kernel<<<DD, 256, 0, stream>>>(r_x, r_y, Np, omega);
    apply_kernel<<<nblocks, 256, 0, stream>>>(x, out);
}

// Round 4
// 307.215 us; speedup vs baseline: 2.0175x; 1.7979x over previous
//
#include <hip/hip_runtime.h>

#define DD 63
#define DD2 (DD * DD)   // 3969
#define NSU 8

// Device-global scratch (rewritten every call -> deterministic).
__device__ float g_F[DD2 * DD];      // f[a][b][c] = g_F[(a*63+b)*63+c]
__device__ float g_B[DD * DD2];      // B[n][j*63+k] = sum_i cc[i,j] f[n,i,k]
__device__ float g_cc[DD2];          // cc = v^T v
__device__ float g_scale;            // N / tr(cc)
__device__ float g_Kt[64 * 64];      // Kt[i][j] (row stride 64): 0.01*(M+H) + 1.01*I

// ---------------------------------------------------------------------------
// fill one Gell-Mann matrix (re/im parts) into an 8x8 region
// ---------------------------------------------------------------------------
__device__ __forceinline__ void fill_L(int a, float (*re)[NSU], float (*im)[NSU]) {
    if (a < 56) {
        int p = a >> 1;
        int j = 0, rem = p;
        while (rem >= 7 - j) { rem -= 7 - j; ++j; }
        int k = j + 1 + rem;
        if ((a & 1) == 0) { re[j][k] = 1.f; re[k][j] = 1.f; }
        else             { im[j][k] = -1.f; im[k][j] = 1.f; }
    } else {
        int l = a - 55;
        float c = sqrtf(2.f / (float)(l * (l + 1)));
        for (int j = 0; j < l; ++j) re[j][j] = c;
        re[l][l] = -(float)l * c;
    }
}

// ---------------------------------------------------------------------------
// Kernel 1: 64 blocks x 256.
//   blocks 0..62 : structure constants f[a,:,:] (wave w does b = 4*rb + w)
//   block 63     : v, cc = v^T v, scale = N / tr(cc)
// ---------------------------------------------------------------------------
__global__ __launch_bounds__(256) void setup_kernel(const float* __restrict__ r_x,
                                                    const float* __restrict__ r_y,
                                                    const float* __restrict__ Np) {
    const int t = threadIdx.x;
    if (blockIdx.x < DD) {
        const int a = blockIdx.x;
        __shared__ float Ar[NSU][NSU], Ai[NSU][NSU];
        __shared__ float Br[4][NSU][NSU], Bi[4][NSU][NSU];
        __shared__ float Cr[4][NSU][NSU], Ci[4][NSU][NSU];
        const int w = t >> 6, lane = t & 63;
        const int r = lane >> 3, c = lane & 7;
        if (t < 64) { Ar[r][c] = 0.f; Ai[r][c] = 0.f; }
        __syncthreads();
        if (t == 0) fill_L(a, Ar, Ai);
        __syncthreads();
        for (int rb = 0; rb < 16; ++rb) {
            const int b = rb * 4 + w;
            const bool act = (b < DD);
            if (act) { Br[w][r][c] = 0.f; Bi[w][r][c] = 0.f; }
            __syncthreads();
            if (act && lane == 0) fill_L(b, Br[w], Bi[w]);
            __syncthreads();
            if (act) {
                float pr = 0.f, pi = 0.f, qr = 0.f, qi = 0.f;
                #pragma unroll
                for (int k = 0; k < NSU; ++k) {
                    pr += Ar[r][k] * Br[w][k][c] - Ai[r][k] * Bi[w][k][c];
                    pi += Ar[r][k] * Bi[w][k][c] + Ai[r][k] * Br[w][k][c];
                    qr += Br[w][r][k] * Ar[k][c] - Bi[w][r][k] * Ai[k][c];
                    qi += Br[w][r][k] * Ai[k][c] + Bi[w][r][k] * Ar[k][c];
                }
                Cr[w][r][c] = pr - qr;
                Ci[w][r][c] = pi - qi;
            }
            __syncthreads();
            if (act && lane < DD) {
                float im;
                if (lane < 56) {
                    int p = lane >> 1;
                    int j = 0, rem = p;
                    while (rem >= 7 - j) { rem -= 7 - j; ++j; }
                    int k = j + 1 + rem;
                    if ((lane & 1) == 0) im = Ci[w][j][k] + Ci[w][k][j];
                    else                 im = Cr[w][j][k] - Cr[w][k][j];
                } else {
                    int l = lane - 55;
                    float cd = sqrtf(2.f / (float)(l * (l + 1)));
                    float s = 0.f;
                    for (int j = 0; j < l; ++j) s += Ci[w][j][j];
                    im = cd * s - (float)l * cd * Ci[w][l][l];
                }
                g_F[(a * DD + b) * DD + lane] = 0.25f * im;
            }
            __syncthreads();
        }
    } else {
        __shared__ float v[DD2];
        __shared__ float ccs[DD2];
        for (int idx = t; idx < DD2; idx += 256) {
            int i = idx / DD, j = idx % DD;
            float val = 0.f;
            if (j > i)       val = r_y[62 * i - (i * (i - 1)) / 2 + (j - i - 1)];
            else if (j == i) val = r_x[63 * i - (i * (i - 1)) / 2];
            v[idx] = val;
        }
        __syncthreads();
        for (int idx = t; idx < DD2; idx += 256) {
            int i = idx / DD, j = idx % DD;
            float s = 0.f;
            for (int k = 0; k < DD; ++k) s = fmaf(v[k * DD + i], v[k * DD + j], s);
            ccs[idx] = s;
            g_cc[idx] = s;
        }
        __syncthreads();
        if (t == 0) {
            float tr = 0.f;
            for (int i = 0; i < DD; ++i) tr += ccs[i * DD + i];
            g_scale = Np[0] / tr;
        }
    }
}

// ---------------------------------------------------------------------------
// Kernel 2: 63 blocks x 256; block n: B[n,j,k] = sum_i cc[i,j] * f[n,i,k].
// cc and f[n] staged in LDS; writes coalesced.
// ---------------------------------------------------------------------------
__global__ __launch_bounds__(256) void buildB_kernel() {
    __shared__ float scc[DD2];
    __shared__ float sf[DD2];
    const int t = threadIdx.x;
    const int n = blockIdx.x;
    for (int idx = t; idx < DD2; idx += 256) {
        scc[idx] = g_cc[idx];
        sf[idx]  = g_F[n * DD2 + idx];
    }
    __syncthreads();
    for (int idx = t; idx < DD2; idx += 256) {
        const int j = idx / DD, k = idx % DD;
        float s = 0.f;
        for (int i = 0; i < DD; ++i) s = fmaf(scc[i * DD + j], sf[i * DD + k], s);
        g_B[n * DD2 + idx] = s;
    }
}

// ---------------------------------------------------------------------------
// Kernel 3: 63*64 blocks x 64; block (m,n): one Kt entry via wave reduce.
//   p = sum_idx f[m,idx] * B[n,idx]   (coalesced, lane-strided)
//   h = sum_k   f[k,m,n] * omega[k]   (one scattered load per lane)
//   Kt[m,n] = 0.01*(-4*scale*p + 8*h) + 1.01*delta(m,n);  col 63 = 0 pad.
// ---------------------------------------------------------------------------
__global__ __launch_bounds__(64) void buildKt_kernel(const float* __restrict__ omega) {
    const int m = blockIdx.x >> 6;          // 0..62
    const int n = blockIdx.x & 63;          // 0..63
    const int lane = threadIdx.x;
    if (n == 63) {
        if (lane == 0) g_Kt[m * 64 + 63] = 0.f;
        return;
    }
    const float* __restrict__ Fm = g_F + m * DD2;
    const float* __restrict__ Bn = g_B + n * DD2;
    float p = 0.f;
    for (int idx = lane; idx < DD2; idx += 64) p = fmaf(Fm[idx], Bn[idx], p);
    float h = (lane < DD) ? g_F[lane * DD2 + m * DD + n] * omega[lane] : 0.f;
    #pragma unroll
    for (int off = 32; off > 0; off >>= 1) {
        p += __shfl_down(p, off);
        h += __shfl_down(h, off);
    }
    if (lane == 0)
        g_Kt[m * 64 + n] = 0.01f * (-4.f * g_scale * p + 8.f * h) + ((m == n) ? 1.01f : 0.f);
}

// ---------------------------------------------------------------------------
// Kernel 4: out[b,i] = sum_j Kt[i][j] * x[b,j].
// Kt staged in LDS (uniform broadcast reads); one batch row per thread.
// ---------------------------------------------------------------------------
__global__ __launch_bounds__(256) void apply_kernel(const float* __restrict__ x,
                                                    float* __restrict__ out) {
    __shared__ __align__(16) float tile[256 * DD];   // 63 KB
    __shared__ __align__(16) float sKt[64 * 64];     // 16 KB
    const int t = threadIdx.x;
    const size_t base = (size_t)blockIdx.x * (256 * DD);

    const float4* __restrict__ gsrc = (const float4*)(x + base);
    float4* __restrict__ ltile = (float4*)tile;
    #pragma unroll
    for (int it = 0; it < 16; ++it) {
        int idx = t + it * 256;
        if (idx < 4032) ltile[idx] = gsrc[idx];
    }
    const float4* __restrict__ gk = (const float4*)g_Kt;
    float4* __restrict__ lk = (float4*)sKt;
    #pragma unroll
    for (int it = 0; it < 4; ++it) lk[t + it * 256] = gk[t + it * 256];
    __syncthreads();

    float xr[DD];
    #pragma unroll
    for (int j = 0; j < DD; ++j) xr[j] = tile[t * DD + j];

    #pragma unroll 2
    for (int i = 0; i < DD; ++i) {
        const float4* __restrict__ kr = (const float4*)(sKt + (i << 6));
        float a0 = 0.f, a1 = 0.f, a2 = 0.f, a3 = 0.f;
        #pragma unroll
        for (int j4 = 0; j4 < 15; ++j4) {
            float4 kv = kr[j4];
            a0 = fmaf(xr[4 * j4 + 0], kv.x, a0);
            a1 = fmaf(xr[4 * j4 + 1], kv.y, a1);
            a2 = fmaf(xr[4 * j4 + 2], kv.z, a2);
            a3 = fmaf(xr[4 * j4 + 3], kv.w, a3);
        }
        float4 kv = kr[15];
        a0 = fmaf(xr[60], kv.x, a0);
        a1 = fmaf(xr[61], kv.y, a1);
        a2 = fmaf(xr[62], kv.z, a2);
        tile[t * DD + i] = (a0 + a1) + (a2 + a3);
    }
    __syncthreads();

    float4* __restrict__ gdst = (float4*)(out + base);
    #pragma unroll
    for (int it = 0; it < 16; ++it) {
        int idx = t + it * 256;
        if (idx < 4032) gdst[idx] = ltile[idx];
    }
}

// ---------------------------------------------------------------------------
extern "C" void kernel_launch(void* const* d_in, const int* in_sizes, int n_in,
                              void* d_out, int out_size, void* d_ws, size_t ws_size,
                              hipStream_t stream) {
    const float* x     = (const float*)d_in[0];
    const float* r_x   = (const float*)d_in[1];
    const float* r_y   = (const float*)d_in[2];
    const float* Np    = (const float*)d_in[3];
    const float* omega = (const float*)d_in[4];
    float* out = (float*)d_out;

    const int rows = in_sizes[0] / DD;          // 1048576
    const int nblocks = rows / 256;             // 4096

    setup_kernel<<<DD + 1, 256, 0, stream>>>(r_x, r_y, Np);
    buildB_kernel<<<DD, 256, 0, stream>>>();
    buildKt_kernel<<<DD * 64, 64, 0, stream>>>(omega);
    apply_kernel<<<nblocks, 256, 0, stream>>>(x, out);
}

// Round 5
// 196.498 us; speedup vs baseline: 3.1542x; 1.5635x over previous
//
#include <hip/hip_runtime.h>

#define DD 63
#define DD2 (DD * DD)   // 3969
#define NSU 8

typedef __attribute__((ext_vector_type(8))) short short8;   // 8 bf16 in 4 VGPRs
typedef __attribute__((ext_vector_type(4))) float f32x4;

// Device-global scratch (rewritten every call -> deterministic).
__device__ float  g_F[DD2 * DD];     // f[a][b][c] = g_F[(a*63+b)*63+c]
__device__ float  g_B[DD * DD2];     // B[n][j*63+k] = sum_i cc[i,j] f[n,i,k]
__device__ float  g_cc[DD2];         // cc = v^T v
__device__ float  g_scale;           // N / tr(cc)
__device__ unsigned short g_Gtb[64 * 64]; // bf16 bits: [k*64+n] = 0.01*G[n][k]; row63/col63 = 0

__device__ __forceinline__ unsigned short f2bf(float f) {
    union { float f; unsigned u; } v; v.f = f;
    unsigned r = v.u + 0x7FFFu + ((v.u >> 16) & 1u);
    return (unsigned short)(r >> 16);
}

// ---------------------------------------------------------------------------
// fill one Gell-Mann matrix (re/im parts) into an 8x8 region
// ---------------------------------------------------------------------------
__device__ __forceinline__ void fill_L(int a, float (*re)[NSU], float (*im)[NSU]) {
    if (a < 56) {
        int p = a >> 1;
        int j = 0, rem = p;
        while (rem >= 7 - j) { rem -= 7 - j; ++j; }
        int k = j + 1 + rem;
        if ((a & 1) == 0) { re[j][k] = 1.f; re[k][j] = 1.f; }
        else             { im[j][k] = -1.f; im[k][j] = 1.f; }
    } else {
        int l = a - 55;
        float c = sqrtf(2.f / (float)(l * (l + 1)));
        for (int j = 0; j < l; ++j) re[j][j] = c;
        re[l][l] = -(float)l * c;
    }
}

// ---------------------------------------------------------------------------
// Kernel 1: 64 blocks x 256.
//   blocks 0..62 : structure constants f[a,:,:] (wave w does b = 4*rb + w)
//   block 63     : v, cc = v^T v, scale = N / tr(cc)
// ---------------------------------------------------------------------------
__global__ __launch_bounds__(256) void setup_kernel(const float* __restrict__ r_x,
                                                    const float* __restrict__ r_y,
                                                    const float* __restrict__ Np) {
    const int t = threadIdx.x;
    if (blockIdx.x < DD) {
        const int a = blockIdx.x;
        __shared__ float Ar[NSU][NSU], Ai[NSU][NSU];
        __shared__ float Br[4][NSU][NSU], Bi[4][NSU][NSU];
        __shared__ float Cr[4][NSU][NSU], Ci[4][NSU][NSU];
        const int w = t >> 6, lane = t & 63;
        const int r = lane >> 3, c = lane & 7;
        if (t < 64) { Ar[r][c] = 0.f; Ai[r][c] = 0.f; }
        __syncthreads();
        if (t == 0) fill_L(a, Ar, Ai);
        __syncthreads();
        for (int rb = 0; rb < 16; ++rb) {
            const int b = rb * 4 + w;
            const bool act = (b < DD);
            if (act) { Br[w][r][c] = 0.f; Bi[w][r][c] = 0.f; }
            __syncthreads();
            if (act && lane == 0) fill_L(b, Br[w], Bi[w]);
            __syncthreads();
            if (act) {
                float pr = 0.f, pi = 0.f, qr = 0.f, qi = 0.f;
                #pragma unroll
                for (int k = 0; k < NSU; ++k) {
                    pr += Ar[r][k] * Br[w][k][c] - Ai[r][k] * Bi[w][k][c];
                    pi += Ar[r][k] * Bi[w][k][c] + Ai[r][k] * Br[w][k][c];
                    qr += Br[w][r][k] * Ar[k][c] - Bi[w][r][k] * Ai[k][c];
                    qi += Br[w][r][k] * Ai[k][c] + Bi[w][r][k] * Ar[k][c];
                }
                Cr[w][r][c] = pr - qr;
                Ci[w][r][c] = pi - qi;
            }
            __syncthreads();
            if (act && lane < DD) {
                float im;
                if (lane < 56) {
                    int p = lane >> 1;
                    int j = 0, rem = p;
                    while (rem >= 7 - j) { rem -= 7 - j; ++j; }
                    int k = j + 1 + rem;
                    if ((lane & 1) == 0) im = Ci[w][j][k] + Ci[w][k][j];
                    else                 im = Cr[w][j][k] - Cr[w][k][j];
                } else {
                    int l = lane - 55;
                    float cd = sqrtf(2.f / (float)(l * (l + 1)));
                    float s = 0.f;
                    for (int j = 0; j < l; ++j) s += Ci[w][j][j];
                    im = cd * s - (float)l * cd * Ci[w][l][l];
                }
                g_F[(a * DD + b) * DD + lane] = 0.25f * im;
            }
            __syncthreads();
        }
    } else {
        __shared__ float v[DD2];
        __shared__ float ccs[DD2];
        for (int idx = t; idx < DD2; idx += 256) {
            int i = idx / DD, j = idx % DD;
            float val = 0.f;
            if (j > i)       val = r_y[62 * i - (i * (i - 1)) / 2 + (j - i - 1)];
            else if (j == i) val = r_x[63 * i - (i * (i - 1)) / 2];
            v[idx] = val;
        }
        __syncthreads();
        for (int idx = t; idx < DD2; idx += 256) {
            int i = idx / DD, j = idx % DD;
            float s = 0.f;
            for (int k = 0; k < DD; ++k) s = fmaf(v[k * DD + i], v[k * DD + j], s);
            ccs[idx] = s;
            g_cc[idx] = s;
        }
        __syncthreads();
        if (t == 0) {
            float tr = 0.f;
            for (int i = 0; i < DD; ++i) tr += ccs[i * DD + i];
            g_scale = Np[0] / tr;
        }
    }
}

// ---------------------------------------------------------------------------
// Kernel 2: 63 blocks x 256; block n: B[n,j,k] = sum_i cc[i,j] * f[n,i,k].
// ---------------------------------------------------------------------------
__global__ __launch_bounds__(256) void buildB_kernel() {
    __shared__ float scc[DD2];
    __shared__ float sf[DD2];
    const int t = threadIdx.x;
    const int n = blockIdx.x;
    for (int idx = t; idx < DD2; idx += 256) {
        scc[idx] = g_cc[idx];
        sf[idx]  = g_F[n * DD2 + idx];
    }
    __syncthreads();
    for (int idx = t; idx < DD2; idx += 256) {
        const int j = idx / DD, k = idx % DD;
        float s = 0.f;
        for (int i = 0; i < DD; ++i) s = fmaf(scc[i * DD + j], sf[i * DD + k], s);
        g_B[n * DD2 + idx] = s;
    }
}

// ---------------------------------------------------------------------------
// Kernel 3: 64*64 blocks x 64; block (m,n): Gs[m][n] -> g_Gtb[n*64+m] (bf16).
//   Gs[m][n] = 0.01*(-4*scale*sum f[m]B[n] + 8*sum_k f[k,m,n] w[k]); pads = 0.
// ---------------------------------------------------------------------------
__global__ __launch_bounds__(64) void buildKt_kernel(const float* __restrict__ omega) {
    const int m = blockIdx.x >> 6;          // out-row 0..63
    const int n = blockIdx.x & 63;          // in-col 0..63
    const int lane = threadIdx.x;
    if (m >= DD || n >= DD) {
        if (lane == 0) g_Gtb[n * 64 + m] = 0;
        return;
    }
    const float* __restrict__ Fm = g_F + m * DD2;
    const float* __restrict__ Bn = g_B + n * DD2;
    float p = 0.f;
    for (int idx = lane; idx < DD2; idx += 64) p = fmaf(Fm[idx], Bn[idx], p);
    float h = (lane < DD) ? g_F[lane * DD2 + m * DD + n] * omega[lane] : 0.f;
    #pragma unroll
    for (int off = 32; off > 0; off >>= 1) {
        p += __shfl_down(p, off);
        h += __shfl_down(h, off);
    }
    if (lane == 0)
        g_Gtb[n * 64 + m] = f2bf(0.01f * (-4.f * g_scale * p + 8.f * h));
}

// ---------------------------------------------------------------------------
// Kernel 4: out[b,:] = 1.01*x[b,:] + x_bf16[b,:] @ (0.01*G)^T  via MFMA.
// Block = 256 rows. Wave w owns rows w*64..w*64+63 (4 m-tiles of 16).
// B-fragments (all of G^T, bf16) live in 32 VGPRs, loaded once from LDS.
// ---------------------------------------------------------------------------
__global__ __launch_bounds__(256) void apply_kernel(const float* __restrict__ x,
                                                    float* __restrict__ out) {
    __shared__ __align__(16) float tile[256 * DD + 16];   // 63 KB + pad
    __shared__ __align__(16) unsigned short sG[64 * 64];  // 8 KB bf16 G^T
    const int t = threadIdx.x;
    const size_t base = (size_t)blockIdx.x * (256 * DD);

    // stage x tile: 16128 contiguous floats, coalesced float4
    const float4* __restrict__ gsrc = (const float4*)(x + base);
    float4* __restrict__ ltile = (float4*)tile;
    #pragma unroll
    for (int it = 0; it < 16; ++it) {
        int idx = t + it * 256;
        if (idx < 4032) ltile[idx] = gsrc[idx];
    }
    // stage G^T bf16: 2048 dwords
    const int* __restrict__ gG = (const int*)g_Gtb;
    int* __restrict__ lG = (int*)sG;
    #pragma unroll
    for (int it = 0; it < 8; ++it) lG[t + it * 256] = gG[t + it * 256];
    __syncthreads();

    const int w = t >> 6, lane = t & 63;
    const int mrow = lane & 15;     // A row / D col within tile
    const int q = lane >> 4;        // 0..3 (k-group / D row-group)

    // B fragments: lane holds B[k=(q*8+j)+32*kt][n=nt*16+mrow]
    short8 bfrag[2][4];
    #pragma unroll
    for (int kt = 0; kt < 2; ++kt)
        #pragma unroll
        for (int nt = 0; nt < 4; ++nt)
            #pragma unroll
            for (int j = 0; j < 8; ++j)
                bfrag[kt][nt][j] = (short)sG[(kt * 32 + q * 8 + j) * 64 + nt * 16 + mrow];

    #pragma unroll
    for (int mt = 0; mt < 4; ++mt) {
        const int row = w * 64 + mt * 16 + mrow;
        const float* __restrict__ ap = tile + row * DD;
        // A fragments: lane holds x_bf[row][k=(q*8+j)+32*kt]
        short8 af[2];
        #pragma unroll
        for (int kt = 0; kt < 2; ++kt)
            #pragma unroll
            for (int j = 0; j < 8; ++j)
                af[kt][j] = (short)f2bf(ap[kt * 32 + q * 8 + j]);

        f32x4 acc[4] = {{0.f,0.f,0.f,0.f},{0.f,0.f,0.f,0.f},
                        {0.f,0.f,0.f,0.f},{0.f,0.f,0.f,0.f}};
        #pragma unroll
        for (int nt = 0; nt < 4; ++nt) {
            acc[nt] = __builtin_amdgcn_mfma_f32_16x16x32_bf16(af[0], bfrag[0][nt], acc[nt], 0, 0, 0);
            acc[nt] = __builtin_amdgcn_mfma_f32_16x16x32_bf16(af[1], bfrag[1][nt], acc[nt], 0, 0, 0);
        }

        // epilogue: D col = lane&15, row = (lane>>4)*4 + reg (m89-verified)
        #pragma unroll
        for (int nt = 0; nt < 4; ++nt) {
            const int ocol = nt * 16 + mrow;
            if (ocol < DD) {
                #pragma unroll
                for (int r = 0; r < 4; ++r) {
                    const int orow = w * 64 + mt * 16 + q * 4 + r;
                    const int idx = orow * DD + ocol;
                    tile[idx] = 1.01f * tile[idx] + acc[nt][r];
                }
            }
        }
    }
    __syncthreads();

    // flush: coalesced float4
    float4* __restrict__ gdst = (float4*)(out + base);
    #pragma unroll
    for (int it = 0; it < 16; ++it) {
        int idx = t + it * 256;
        if (idx < 4032) gdst[idx] = ltile[idx];
    }
}

// ---------------------------------------------------------------------------
extern "C" void kernel_launch(void* const* d_in, const int* in_sizes, int n_in,
                              void* d_out, int out_size, void* d_ws, size_t ws_size,
                              hipStream_t stream) {
    const float* x     = (const float*)d_in[0];
    const float* r_x   = (const float*)d_in[1];
    const float* r_y   = (const float*)d_in[2];
    const float* Np    = (const float*)d_in[3];
    const float* omega = (const float*)d_in[4];
    float* out = (float*)d_out;

    const int rows = in_sizes[0] / DD;          // 1048576
    const int nblocks = rows / 256;             // 4096

    setup_kernel<<<DD + 1, 256, 0, stream>>>(r_x, r_y, Np);
    buildB_kernel<<<DD, 256, 0, stream>>>();
    buildKt_kernel<<<64 * 64, 64, 0, stream>>>(omega);
    apply_kernel<<<nblocks, 256, 0, stream>>>(x, out);
}

// Round 6
// 183.764 us; speedup vs baseline: 3.3728x; 1.0693x over previous
//
#include <hip/hip_runtime.h>
#include <hip/hip_bf16.h>

#define DD 63
#define DD2 (DD * DD)   // 3969
#define NSU 8
#define TROWS 128       // batch rows per block in apply

typedef __attribute__((ext_vector_type(8))) short short8;   // 8 bf16 in 4 VGPRs
typedef __attribute__((ext_vector_type(4))) float f32x4;

// Device-global scratch (rewritten every call -> deterministic).
__device__ float  g_F[DD2 * DD];     // f[a][b][c] = g_F[(a*63+b)*63+c]
__device__ float  g_B[DD * DD2];     // B[n][j*63+k] = sum_i cc[i,j] f[n,i,k]
__device__ float  g_cc[DD2];         // cc = v^T v
__device__ float  g_scale;           // N / tr(cc)
__device__ unsigned short g_Gb[64 * 64]; // bf16 bits, ROW-major: [m*64+k] = 0.01*G[m][k]; row/col 63 = 0

__device__ __forceinline__ unsigned short f2bf(float f) {
    union { float f; unsigned u; } v; v.f = f;
    unsigned r = v.u + 0x7FFFu + ((v.u >> 16) & 1u);
    return (unsigned short)(r >> 16);
}

// ---------------------------------------------------------------------------
// fill one Gell-Mann matrix (re/im parts) into an 8x8 region
// ---------------------------------------------------------------------------
__device__ __forceinline__ void fill_L(int a, float (*re)[NSU], float (*im)[NSU]) {
    if (a < 56) {
        int p = a >> 1;
        int j = 0, rem = p;
        while (rem >= 7 - j) { rem -= 7 - j; ++j; }
        int k = j + 1 + rem;
        if ((a & 1) == 0) { re[j][k] = 1.f; re[k][j] = 1.f; }
        else             { im[j][k] = -1.f; im[k][j] = 1.f; }
    } else {
        int l = a - 55;
        float c = sqrtf(2.f / (float)(l * (l + 1)));
        for (int j = 0; j < l; ++j) re[j][j] = c;
        re[l][l] = -(float)l * c;
    }
}

// ---------------------------------------------------------------------------
// Kernel 1: 64 blocks x 256.
//   blocks 0..62 : structure constants f[a,:,:] (wave w does b = 4*rb + w)
//   block 63     : v, cc = v^T v, scale = N / tr(cc)
// ---------------------------------------------------------------------------
__global__ __launch_bounds__(256) void setup_kernel(const float* __restrict__ r_x,
                                                    const float* __restrict__ r_y,
                                                    const float* __restrict__ Np) {
    const int t = threadIdx.x;
    if (blockIdx.x < DD) {
        const int a = blockIdx.x;
        __shared__ float Ar[NSU][NSU], Ai[NSU][NSU];
        __shared__ float Br[4][NSU][NSU], Bi[4][NSU][NSU];
        __shared__ float Cr[4][NSU][NSU], Ci[4][NSU][NSU];
        const int w = t >> 6, lane = t & 63;
        const int r = lane >> 3, c = lane & 7;
        if (t < 64) { Ar[r][c] = 0.f; Ai[r][c] = 0.f; }
        __syncthreads();
        if (t == 0) fill_L(a, Ar, Ai);
        __syncthreads();
        for (int rb = 0; rb < 16; ++rb) {
            const int b = rb * 4 + w;
            const bool act = (b < DD);
            if (act) { Br[w][r][c] = 0.f; Bi[w][r][c] = 0.f; }
            __syncthreads();
            if (act && lane == 0) fill_L(b, Br[w], Bi[w]);
            __syncthreads();
            if (act) {
                float pr = 0.f, pi = 0.f, qr = 0.f, qi = 0.f;
                #pragma unroll
                for (int k = 0; k < NSU; ++k) {
                    pr += Ar[r][k] * Br[w][k][c] - Ai[r][k] * Bi[w][k][c];
                    pi += Ar[r][k] * Bi[w][k][c] + Ai[r][k] * Br[w][k][c];
                    qr += Br[w][r][k] * Ar[k][c] - Bi[w][r][k] * Ai[k][c];
                    qi += Br[w][r][k] * Ai[k][c] + Bi[w][r][k] * Ar[k][c];
                }
                Cr[w][r][c] = pr - qr;
                Ci[w][r][c] = pi - qi;
            }
            __syncthreads();
            if (act && lane < DD) {
                float im;
                if (lane < 56) {
                    int p = lane >> 1;
                    int j = 0, rem = p;
                    while (rem >= 7 - j) { rem -= 7 - j; ++j; }
                    int k = j + 1 + rem;
                    if ((lane & 1) == 0) im = Ci[w][j][k] + Ci[w][k][j];
                    else                 im = Cr[w][j][k] - Cr[w][k][j];
                } else {
                    int l = lane - 55;
                    float cd = sqrtf(2.f / (float)(l * (l + 1)));
                    float s = 0.f;
                    for (int j = 0; j < l; ++j) s += Ci[w][j][j];
                    im = cd * s - (float)l * cd * Ci[w][l][l];
                }
                g_F[(a * DD + b) * DD + lane] = 0.25f * im;
            }
            __syncthreads();
        }
    } else {
        __shared__ float v[DD2];
        __shared__ float ccs[DD2];
        for (int idx = t; idx < DD2; idx += 256) {
            int i = idx / DD, j = idx % DD;
            float val = 0.f;
            if (j > i)       val = r_y[62 * i - (i * (i - 1)) / 2 + (j - i - 1)];
            else if (j == i) val = r_x[63 * i - (i * (i - 1)) / 2];
            v[idx] = val;
        }
        __syncthreads();
        for (int idx = t; idx < DD2; idx += 256) {
            int i = idx / DD, j = idx % DD;
            float s = 0.f;
            for (int k = 0; k < DD; ++k) s = fmaf(v[k * DD + i], v[k * DD + j], s);
            ccs[idx] = s;
            g_cc[idx] = s;
        }
        __syncthreads();
        if (t == 0) {
            float tr = 0.f;
            for (int i = 0; i < DD; ++i) tr += ccs[i * DD + i];
            g_scale = Np[0] / tr;
        }
    }
}

// ---------------------------------------------------------------------------
// Kernel 2: 63 blocks x 256; block n: B[n,j,k] = sum_i cc[i,j] * f[n,i,k].
// ---------------------------------------------------------------------------
__global__ __launch_bounds__(256) void buildB_kernel() {
    __shared__ float scc[DD2];
    __shared__ float sf[DD2];
    const int t = threadIdx.x;
    const int n = blockIdx.x;
    for (int idx = t; idx < DD2; idx += 256) {
        scc[idx] = g_cc[idx];
        sf[idx]  = g_F[n * DD2 + idx];
    }
    __syncthreads();
    for (int idx = t; idx < DD2; idx += 256) {
        const int j = idx / DD, k = idx % DD;
        float s = 0.f;
        for (int i = 0; i < DD; ++i) s = fmaf(scc[i * DD + j], sf[i * DD + k], s);
        g_B[n * DD2 + idx] = s;
    }
}

// ---------------------------------------------------------------------------
// Kernel 3: 64*64 blocks x 64; block (m,n): G[m][n] -> g_Gb[m*64+n] (bf16).
//   G[m][n] = 0.01*(-4*scale*sum f[m]B[n] + 8*sum_k f[k,m,n] w[k]); pads = 0.
// ---------------------------------------------------------------------------
__global__ __launch_bounds__(64) void buildKt_kernel(const float* __restrict__ omega) {
    const int m = blockIdx.x >> 6;          // out-row 0..63
    const int n = blockIdx.x & 63;          // in-col (k) 0..63
    const int lane = threadIdx.x;
    if (m >= DD || n >= DD) {
        if (lane == 0) g_Gb[m * 64 + n] = 0;
        return;
    }
    const float* __restrict__ Fm = g_F + m * DD2;
    const float* __restrict__ Bn = g_B + n * DD2;
    float p = 0.f;
    for (int idx = lane; idx < DD2; idx += 64) p = fmaf(Fm[idx], Bn[idx], p);
    float h = (lane < DD) ? g_F[lane * DD2 + m * DD + n] * omega[lane] : 0.f;
    #pragma unroll
    for (int off = 32; off > 0; off >>= 1) {
        p += __shfl_down(p, off);
        h += __shfl_down(h, off);
    }
    if (lane == 0)
        g_Gb[m * 64 + n] = f2bf(0.01f * (-4.f * g_scale * p + 8.f * h));
}

// ---------------------------------------------------------------------------
// Kernel 4: out[b,:] = 1.01*x[b,:] + x_bf16[b,:] @ (0.01*G)^T  via MFMA.
// 128 rows/block -> 40.4 KB LDS -> 4 blocks/CU. Wave w owns rows w*32..+31
// (2 m-tiles of 16). B-fragments (all of G, bf16 [m][k] row-major) = 8
// aligned ds_read_b128, resident in 32 VGPRs.
// ---------------------------------------------------------------------------
__global__ __launch_bounds__(256, 4) void apply_kernel(const float* __restrict__ x,
                                                       float* __restrict__ out) {
    __shared__ __align__(16) float tile[TROWS * DD];      // 32256 B
    __shared__ __align__(16) unsigned short sG[64 * 64];  // 8192 B
    const int t = threadIdx.x;
    const size_t base = (size_t)blockIdx.x * (TROWS * DD);

    // stage x tile: 8064 contiguous floats = 2016 float4, coalesced
    const float4* __restrict__ gsrc = (const float4*)(x + base);
    float4* __restrict__ ltile = (float4*)tile;
    #pragma unroll
    for (int it = 0; it < 8; ++it) {
        int idx = t + it * 256;
        if (idx < (TROWS * DD / 4)) ltile[idx] = gsrc[idx];
    }
    // stage G (bf16, row-major [m][k]): 8 KB = 512 int4
    const int4* __restrict__ gG = (const int4*)g_Gb;
    int4* __restrict__ lG = (int4*)sG;
    lG[t]       = gG[t];
    lG[t + 256] = gG[t + 256];
    __syncthreads();

    const int w = t >> 6, lane = t & 63;
    const int mrow = lane & 15;     // A row / D col within 16-tile
    const int q = lane >> 4;        // 0..3 (k-group / D row-group)

    // B fragments: lane holds B[k=kt*32+q*8+j][n=nt*16+mrow] = G[n][k]
    // = 8 consecutive bf16 of sG row (nt*16+mrow) -> one 16B aligned load each
    short8 bfrag[2][4];
    #pragma unroll
    for (int kt = 0; kt < 2; ++kt)
        #pragma unroll
        for (int nt = 0; nt < 4; ++nt)
            bfrag[kt][nt] = *(const short8*)&sG[(nt * 16 + mrow) * 64 + kt * 32 + q * 8];

    #pragma unroll
    for (int mt = 0; mt < 2; ++mt) {
        const int row = w * 32 + mt * 16 + mrow;
        const float* __restrict__ ap = tile + row * DD;
        // A fragments: x_bf[row][k]; k==63 clamped (pairs with G[n][63]==0)
        short8 af[2];
        #pragma unroll
        for (int kt = 0; kt < 2; ++kt)
            #pragma unroll
            for (int j = 0; j < 8; ++j) {
                int k = kt * 32 + q * 8 + j;
                float v = ap[(k == 63) ? 62 : k];
                __hip_bfloat16 h = __float2bfloat16(v);   // -> v_cvt_pk_bf16_f32 pairs
                af[kt][j] = *reinterpret_cast<short*>(&h);
            }

        f32x4 acc[4] = {{0.f,0.f,0.f,0.f},{0.f,0.f,0.f,0.f},
                        {0.f,0.f,0.f,0.f},{0.f,0.f,0.f,0.f}};
        #pragma unroll
        for (int nt = 0; nt < 4; ++nt) {
            acc[nt] = __builtin_amdgcn_mfma_f32_16x16x32_bf16(af[0], bfrag[0][nt], acc[nt], 0, 0, 0);
            acc[nt] = __builtin_amdgcn_mfma_f32_16x16x32_bf16(af[1], bfrag[1][nt], acc[nt], 0, 0, 0);
        }

        // epilogue: D col = lane&15, row = (lane>>4)*4 + reg (m89-verified)
        #pragma unroll
        for (int nt = 0; nt < 4; ++nt) {
            const int ocol = nt * 16 + mrow;
            if (ocol < DD) {
                #pragma unroll
                for (int r = 0; r < 4; ++r) {
                    const int orow = w * 32 + mt * 16 + q * 4 + r;
                    const int idx = orow * DD + ocol;
                    tile[idx] = 1.01f * tile[idx] + acc[nt][r];
                }
            }
        }
    }
    __syncthreads();

    // flush: coalesced float4
    float4* __restrict__ gdst = (float4*)(out + base);
    #pragma unroll
    for (int it = 0; it < 8; ++it) {
        int idx = t + it * 256;
        if (idx < (TROWS * DD / 4)) gdst[idx] = ltile[idx];
    }
}

// ---------------------------------------------------------------------------
extern "C" void kernel_launch(void* const* d_in, const int* in_sizes, int n_in,
                              void* d_out, int out_size, void* d_ws, size_t ws_size,
                              hipStream_t stream) {
    const float* x     = (const float*)d_in[0];
    const float* r_x   = (const float*)d_in[1];
    const float* r_y   = (const float*)d_in[2];
    const float* Np    = (const float*)d_in[3];
    const float* omega = (const float*)d_in[4];
    float* out = (float*)d_out;

    const int rows = in_sizes[0] / DD;          // 1048576
    const int nblocks = rows / TROWS;           // 8192

    setup_kernel<<<DD + 1, 256, 0, stream>>>(r_x, r_y, Np);
    buildB_kernel<<<DD, 256, 0, stream>>>();
    buildKt_kernel<<<64 * 64, 64, 0, stream>>>(omega);
    apply_kernel<<<nblocks, 256, 0, stream>>>(x, out);
}